// Round 7
// baseline (146.450 us; speedup 1.0000x reference)
//
#include <hip/hip_runtime.h>
#include <hip/hip_bf16.h>

typedef __attribute__((ext_vector_type(8))) short s8v;   // 8 x bf16 = 4 VGPR
typedef __attribute__((ext_vector_type(4))) short s4v;   // 4 x bf16 = 2 VGPR
typedef __attribute__((ext_vector_type(4))) float f4v;   // 4 x f32

static __device__ __forceinline__ short f2bf(float f){
  unsigned int u = __float_as_uint(f);
  u = (u + 0x7FFFu + ((u >> 16) & 1u)) >> 16;   // RNE f32 -> bf16
  return (short)u;
}

static __device__ __forceinline__ s4v pack4(float a, float b, float c, float d){
  union { s4v v; __hip_bfloat162 h[2]; } u;
  u.h[0] = __float22bfloat162_rn(make_float2(a, b));
  u.h[1] = __float22bfloat162_rn(make_float2(c, d));
  return u.v;
}

static __device__ __forceinline__ f4v mfma16(s4v a, s4v b, f4v c){
  return __builtin_amdgcn_mfma_f32_16x16x16bf16_1k(a, b, c, 0, 0, 0);
}

// ---------- K1: h = x @ W (8 rows per wave) ----------
__global__ __launch_bounds__(256) void k_h(const float* __restrict__ x,
                                           const float* __restrict__ W,
                                           float* __restrict__ h){
  int wid = threadIdx.x >> 6, lane = threadIdx.x & 63;
  int r0 = (blockIdx.x * 4 + wid) * 8;
  const float* xr = x + (size_t)r0 * 512;
  float acc[8] = {0.f,0.f,0.f,0.f,0.f,0.f,0.f,0.f};
  #pragma unroll 4
  for (int k = 0; k < 512; ++k){
    float wv = W[k*64 + lane];
    #pragma unroll
    for (int r = 0; r < 8; ++r)
      acc[r] = fmaf(xr[(size_t)r*512 + k], wv, acc[r]);
  }
  #pragma unroll
  for (int r = 0; r < 8; ++r)
    h[(size_t)(r0 + r)*64 + lane] = acc[r];
}

// ---------- K2: per-64-row tile: swizzled V frags, per-row F/EG/V2, block partials ----------
__global__ __launch_bounds__(256) void k_prep(const float* __restrict__ h,
                                              const float* __restrict__ a,
                                              short* __restrict__ VbfSw,
                                              short* __restrict__ VTsw,
                                              float* __restrict__ F,
                                              float2* __restrict__ EG,
                                              float* __restrict__ V2arr,
                                              float* __restrict__ Pv2,
                                              float* __restrict__ Pg,
                                              float* __restrict__ Vpart){
  __shared__ float t[64][65];
  const int tid = threadIdx.x;
  const int lane = tid & 63, w = tid >> 6;
  const int lo = lane & 15, hi = lane >> 4;
  const int i0 = blockIdx.x * 64;
  #pragma unroll
  for (int it = 0; it < 16; ++it){
    int r = w * 16 + it;
    t[r][lane] = h[(size_t)(i0 + r) * 64 + lane];
  }
  __syncthreads();
  // VbfSw: dot A-frag layout
  #pragma unroll
  for (int ks = 0; ks < 2; ++ks){
    s8v o;
    #pragma unroll
    for (int e = 0; e < 8; ++e)
      o[e] = f2bf(t[w*16 + lo][ks*32 + hi*8 + e]);
    *(s8v*)(VbfSw + ((size_t)(i0/16 + w)*2 + ks)*512 + lane*8) = o;
  }
  // VTsw: PV A-frag layout
  const int p = w >> 1;
  #pragma unroll
  for (int oo = 0; oo < 2; ++oo){
    const int ot = (w & 1) * 2 + oo;
    s8v o;
    #pragma unroll
    for (int e = 0; e < 8; ++e){
      int parity = e >> 2, q = e & 3;
      o[e] = f2bf(t[(p*2 + parity)*16 + hi*4 + q][ot*16 + lo]);
    }
    *(s8v*)(VTsw + ((size_t)(i0/32 + p)*4 + ot)*512 + lane*8) = o;
  }
  // per-row stats + block partials + colsum (wave 0)
  if (tid < 64){
    const int r = tid;
    float f = 0.f, g = 0.f, v2 = 0.f;
    #pragma unroll 8
    for (int o = 0; o < 64; ++o){
      float hv = t[r][o];
      f  = fmaf(hv, a[o],      f);
      g  = fmaf(hv, a[64 + o], g);
      v2 = fmaf(hv, hv,        v2);
    }
    const int row = i0 + r;
    F[row] = f;
    V2arr[row] = v2;
    EG[row] = make_float2(__expf(g), __expf(0.2f * g));
    float vmin = v2, gmx = g;
    #pragma unroll
    for (int off = 32; off; off >>= 1){
      vmin = fminf(vmin, __shfl_xor(vmin, off));
      gmx  = fmaxf(gmx,  __shfl_xor(gmx,  off));
    }
    if (r == 0){ Pv2[blockIdx.x] = vmin; Pg[blockIdx.x] = gmx; }
    float cs = 0.f;
    #pragma unroll 8
    for (int rr = 0; rr < 64; ++rr) cs += t[rr][tid];
    Vpart[(size_t)blockIdx.x * 64 + tid] = cs;
  }
}

// ---------- K3: fully fused, 2-way tile-unrolled hot loops (independent register
// streams per tile pair -> 2x ILP against exposed load/MFMA latency). ----------
__global__ __launch_bounds__(512, 4) void k_fused(
    const int* __restrict__ adj,
    const float2* __restrict__ EG, const float* __restrict__ V2arr,
    const float* __restrict__ F,
    const float* __restrict__ Pv2, const float* __restrict__ Pg,
    const float* __restrict__ Vpart,
    const short* __restrict__ VbfSw, const short* __restrict__ VTsw,
    float* __restrict__ out)
{
  __shared__ float numT[8][64][16];
  __shared__ float denL[8][16];
  __shared__ float Mlds[16][68];
  __shared__ float M1L[16][68];
  __shared__ __align__(16) short Mb16[16][64];
  __shared__ float CiL[16], rm2L[16], uaiL[16];
  __shared__ float VmeanL[64];
  __shared__ float gmaxS, v2minS;
  __shared__ int actL, chgL, emptyL;

  const int tid  = threadIdx.x;
  const int w    = tid >> 6;
  const int lane = tid & 63;
  const int lo = lane & 15, hi = lane >> 4;
  const int r0 = blockIdx.x << 4;
  const int i  = r0 + lo;

  // global min/max from per-block partials (no atomics)
  if (tid < 64){
    float v = fminf(Pv2[tid], Pv2[tid + 64]);
    float g = fmaxf(Pg[tid],  Pg[tid + 64]);
    #pragma unroll
    for (int off = 32; off; off >>= 1){
      v = fminf(v, __shfl_xor(v, off));
      g = fmaxf(g, __shfl_xor(g, off));
    }
    if (tid == 0){ v2minS = v; gmaxS = g; actL = 0; emptyL = 0; }
  }
  __syncthreads();

  const float fi   = F[i];
  const float gmax = gmaxS;
  const float z    = fi + gmax;
  const float B    = fmaxf(z, 0.2f * z);          // >= leaky(fi+gj) for all j
  const float e1s  = __expf(fi - B);
  const float e2s  = __expf(0.2f * fi - B);

  const int* arow = adj + (size_t)i * 8192 + hi*4;

  const f4v zero4 = {0.f,0.f,0.f,0.f};
  f4v pacc[4] = {zero4, zero4, zero4, zero4};
  float pden = 0.f;

  // ---- Phase AB: 2 tiles per iteration, disjoint register streams ----
  for (int cc = w; cc < 128; cc += 16){
    const int cA = cc, cB = cc + 8;
    int4 avA[4], avB[4];
    {
      const int* apA = arow + (cA << 6);
      const int* apB = arow + (cB << 6);
      #pragma unroll
      for (int nt = 0; nt < 4; ++nt) avA[nt] = *(const int4*)(apA + nt*16);
      #pragma unroll
      for (int nt = 0; nt < 4; ++nt) avB[nt] = *(const int4*)(apB + nt*16);
    }
    s4v wwA[4], wwB[4];
    #pragma unroll
    for (int nt = 0; nt < 4; ++nt){
      const int jb = (cA << 6) + nt*16 + hi*4;
      const int ab[4] = {avA[nt].x, avA[nt].y, avA[nt].z, avA[nt].w};
      const f4v u0 = *(const f4v*)(EG + jb);
      const f4v u1 = *(const f4v*)(EG + jb + 2);
      const float ega[4] = {u0[0], u0[2], u1[0], u1[2]};
      const float egb[4] = {u0[1], u0[3], u1[1], u1[3]};
      float wwv[4];
      #pragma unroll
      for (int q = 0; q < 4; ++q){
        float u = fmaxf(e1s * ega[q], e2s * egb[q]);
        u = ab[q] ? u : 0.f;
        pden += u;
        wwv[q] = u;
      }
      wwA[nt] = pack4(wwv[0], wwv[1], wwv[2], wwv[3]);
    }
    #pragma unroll
    for (int nt = 0; nt < 4; ++nt){
      const int jb = (cB << 6) + nt*16 + hi*4;
      const int ab[4] = {avB[nt].x, avB[nt].y, avB[nt].z, avB[nt].w};
      const f4v u0 = *(const f4v*)(EG + jb);
      const f4v u1 = *(const f4v*)(EG + jb + 2);
      const float ega[4] = {u0[0], u0[2], u1[0], u1[2]};
      const float egb[4] = {u0[1], u0[3], u1[1], u1[3]};
      float wwv[4];
      #pragma unroll
      for (int q = 0; q < 4; ++q){
        float u = fmaxf(e1s * ega[q], e2s * egb[q]);
        u = ab[q] ? u : 0.f;
        pden += u;
        wwv[q] = u;
      }
      wwB[nt] = pack4(wwv[0], wwv[1], wwv[2], wwv[3]);
    }
    const short* vtA = VTsw + (size_t)cA*4096 + lane*8;
    const short* vtB = VTsw + (size_t)cB*4096 + lane*8;
    #pragma unroll
    for (int p = 0; p < 2; ++p){
      #pragma unroll
      for (int ot = 0; ot < 4; ++ot){
        s8v v8A = *(const s8v*)(vtA + (p*4 + ot)*512);
        s8v v8B = *(const s8v*)(vtB + (p*4 + ot)*512);
        s4v aLoA = {v8A[0], v8A[1], v8A[2], v8A[3]};
        s4v aHiA = {v8A[4], v8A[5], v8A[6], v8A[7]};
        s4v aLoB = {v8B[0], v8B[1], v8B[2], v8B[3]};
        s4v aHiB = {v8B[4], v8B[5], v8B[6], v8B[7]};
        pacc[ot] = mfma16(aLoA, wwA[2*p],   pacc[ot]);
        pacc[ot] = mfma16(aLoB, wwB[2*p],   pacc[ot]);
        pacc[ot] = mfma16(aHiA, wwA[2*p+1], pacc[ot]);
        pacc[ot] = mfma16(aHiB, wwB[2*p+1], pacc[ot]);
      }
    }
  }

  pden += __shfl_xor(pden, 16);
  pden += __shfl_xor(pden, 32);
  if (lane < 16) denL[w][lane] = pden;
  #pragma unroll
  for (int ot = 0; ot < 4; ++ot)
    #pragma unroll
    for (int q = 0; q < 4; ++q)
      numT[w][ot*16 + hi*4 + q][lo] = pacc[ot][q];
  __syncthreads();

  // ---- reduce -> M1, Ci, empty detection ----
  {
    const int ii = tid & 15;
    const int o  = tid >> 4;            // 0..31
    float den = 0.f;
    #pragma unroll
    for (int w2 = 0; w2 < 8; ++w2) den += denL[w2][ii];
    if (o == 0){
      uaiL[ii] = (den <= 0.f) ? (1.0f / 8192.0f) : 0.f;
      if (den <= 0.f) emptyL = 1;
    }
    den = fmaxf(den, 1e-30f);
    const float rden = 1.0f / den;
    #pragma unroll
    for (int rep = 0; rep < 2; ++rep){
      const int oo = o + rep*32;
      float num = 0.f;
      #pragma unroll
      for (int w2 = 0; w2 < 8; ++w2) num += numT[w2][oo][ii];
      Mlds[ii][oo] = num * rden;
    }
    if (tid < 16){
      float fb = F[r0 + tid];
      float zb = fb + gmax;
      float Bb = fmaxf(zb, 0.2f * zb);
      CiL[tid] = Bb + __logf(den);      // softmax log-normalizer
    }
  }
  __syncthreads();

  // ---- empty-row fixup: M1 = colmean(V) (uniform attention) ----
  if (emptyL){
    if (tid < 64){
      float s = 0.f;
      for (int b = 0; b < 128; ++b) s += Vpart[(size_t)b*64 + tid];
      VmeanL[tid] = s * (1.0f / 8192.0f);
    }
    __syncthreads();
    {
      const int r = tid >> 5, c2 = (tid & 31) << 1;
      if (uaiL[r] > 0.f){ Mlds[r][c2] = VmeanL[c2]; Mlds[r][c2+1] = VmeanL[c2+1]; }
    }
    __syncthreads();
  }

  // ---- rm2 + activity (Cauchy-Schwarz: row inactive if sqrt(rm2) <= sqrt(v2min)-3.85) ----
  if (tid < 16){
    float s2 = 0.f;
    #pragma unroll 8
    for (int o = 0; o < 64; ++o) s2 = fmaf(Mlds[tid][o], Mlds[tid][o], s2);
    rm2L[tid] = s2;
    if (sqrtf(s2) > sqrtf(v2minS) - 3.85f) actL = 1;
  }
  __syncthreads();

  if (actL){
    {
      const int r = tid >> 5, c2 = (tid & 31) << 1;
      float a0 = Mlds[r][c2], a1 = Mlds[r][c2+1];
      M1L[r][c2] = a0;  M1L[r][c2+1] = a1;
      Mb16[r][c2] = f2bf(a0); Mb16[r][c2+1] = f2bf(a1);
    }
    const float e1c = __expf(fi - CiL[lo]);
    const float e2c = __expf(0.2f * fi - CiL[lo]);
    const float uai = uaiL[lo];
    __syncthreads();

    for (int pass = 0; pass < 3; ++pass){
      if (tid == 0) chgL = 0;
      __syncthreads();
      const float rm2 = rm2L[lo];
      s8v bM[2];
      #pragma unroll
      for (int ks = 0; ks < 2; ++ks)
        bM[ks] = *(const s8v*)&Mb16[lo][ks*32 + hi*8];

      f4v cacc[4] = {zero4, zero4, zero4, zero4};
      float cden = 0.f;

      // slow path for one tile (d2 passed in-place in acc)
      auto slowpath = [&](int c, f4v* d2s){
        const int* ap = arow + (c << 6);
        s4v wwpk[4];
        #pragma unroll
        for (int nt = 0; nt < 4; ++nt){
          const int jb = (c << 6) + nt*16 + hi*4;
          const int4 av4 = *(const int4*)(ap + nt*16);
          const int ab[4] = {av4.x, av4.y, av4.z, av4.w};
          const f4v u0 = *(const f4v*)(EG + jb);
          const f4v u1 = *(const f4v*)(EG + jb + 2);
          const float ega[4] = {u0[0], u0[2], u1[0], u1[2]};
          const float egb[4] = {u0[1], u0[3], u1[1], u1[3]};
          float wwv[4];
          #pragma unroll
          for (int q = 0; q < 4; ++q){
            float A = fmaxf(e1c * ega[q], e2c * egb[q]);
            A = ab[q] ? A : uai;
            float dist  = sqrtf(fmaxf(d2s[nt][q], 0.f));
            float delta = fmaxf(__builtin_amdgcn_rcpf(dist + 0.01f) - 0.26f, 0.f);
            float ww = delta * A;
            cden += ww;
            wwv[q] = ww;
          }
          wwpk[nt] = pack4(wwv[0], wwv[1], wwv[2], wwv[3]);
        }
        const short* vt = VTsw + (size_t)c*4096 + lane*8;
        #pragma unroll
        for (int p = 0; p < 2; ++p){
          #pragma unroll
          for (int ot = 0; ot < 4; ++ot){
            s8v v8 = *(const s8v*)(vt + (p*4 + ot)*512);
            s4v aLo = {v8[0], v8[1], v8[2], v8[3]};
            s4v aHi = {v8[4], v8[5], v8[6], v8[7]};
            cacc[ot] = mfma16(aLo, wwpk[2*p],   cacc[ot]);
            cacc[ot] = mfma16(aHi, wwpk[2*p+1], cacc[ot]);
          }
        }
      };

      for (int cc = w; cc < 128; cc += 16){
        const int cA = cc, cB = cc + 8;
        // dot for both tiles: independent MFMA chains interleaved
        f4v accA[4] = {zero4, zero4, zero4, zero4};
        f4v accB[4] = {zero4, zero4, zero4, zero4};
        const short* vbA = VbfSw + (size_t)cA*4096 + lane*8;
        const short* vbB = VbfSw + (size_t)cB*4096 + lane*8;
        #pragma unroll
        for (int nt = 0; nt < 4; ++nt){
          #pragma unroll
          for (int ks = 0; ks < 2; ++ks){
            s8v avA = *(const s8v*)(vbA + (nt*2 + ks)*512);
            s8v avB = *(const s8v*)(vbB + (nt*2 + ks)*512);
            accA[nt] = __builtin_amdgcn_mfma_f32_16x16x32_bf16(avA, bM[ks], accA[nt], 0, 0, 0);
            accB[nt] = __builtin_amdgcn_mfma_f32_16x16x32_bf16(avB, bM[ks], accB[nt], 0, 0, 0);
          }
        }
        // d2 in place; trigger per tile
        float dmA = 1e30f, dmB = 1e30f;
        #pragma unroll
        for (int nt = 0; nt < 4; ++nt){
          const int jbA = (cA << 6) + nt*16 + hi*4;
          const int jbB = (cB << 6) + nt*16 + hi*4;
          const f4v v2qA = *(const f4v*)(V2arr + jbA);
          const f4v v2qB = *(const f4v*)(V2arr + jbB);
          #pragma unroll
          for (int q = 0; q < 4; ++q){
            const float dA = fmaf(-2.0f, accA[nt][q], rm2 + v2qA[q]);
            const float dB = fmaf(-2.0f, accB[nt][q], rm2 + v2qB[q]);
            accA[nt][q] = dA; accB[nt][q] = dB;
            dmA = fminf(dmA, dA); dmB = fminf(dmB, dB);
          }
        }
        if (__any(dmA < 16.0f)) slowpath(cA, accA);
        if (__any(dmB < 16.0f)) slowpath(cB, accB);
      }

      if (__any(cden > 0.f)) chgL = 1;
      __syncthreads();
      if (chgL){
        float cd = cden;
        cd += __shfl_xor(cd, 16);
        cd += __shfl_xor(cd, 32);
        if (lane < 16) denL[w][lane] = cd;
        #pragma unroll
        for (int ot = 0; ot < 4; ++ot)
          #pragma unroll
          for (int q = 0; q < 4; ++q)
            numT[w][ot*16 + hi*4 + q][lo] = cacc[ot][q];
        __syncthreads();
        {
          const int ii = tid & 15;
          const int o  = tid >> 4;
          float den = 0.f;
          #pragma unroll
          for (int w2 = 0; w2 < 8; ++w2) den += denL[w2][ii];
          const float rden = 1.0f / (0.01f + den);
          #pragma unroll
          for (int rep = 0; rep < 2; ++rep){
            const int oo = o + rep*32;
            float num = 0.f;
            #pragma unroll
            for (int w2 = 0; w2 < 8; ++w2) num += numT[w2][oo][ii];
            Mlds[ii][oo] = fmaf(0.01f, M1L[ii][oo], num) * rden;
          }
        }
        __syncthreads();
        {
          const int r = tid >> 5, c2 = (tid & 31) << 1;
          Mb16[r][c2]   = f2bf(Mlds[r][c2]);
          Mb16[r][c2+1] = f2bf(Mlds[r][c2+1]);
        }
        if (tid < 16){
          float s2 = 0.f;
          #pragma unroll 8
          for (int o = 0; o < 64; ++o) s2 = fmaf(Mlds[tid][o], Mlds[tid][o], s2);
          rm2L[tid] = s2;
        }
        __syncthreads();
      }
    }
  }
  __syncthreads();

  // ---- epilogue: elu -> out ----
  #pragma unroll
  for (int rr = 0; rr < 2; ++rr){
    const int ir = w*2 + rr;
    const float v = Mlds[ir][lane];
    out[(size_t)(r0 + ir) * 64 + lane] = (v > 0.f) ? v : (__expf(v) - 1.0f);
  }
}

extern "C" void kernel_launch(void* const* d_in, const int* in_sizes, int n_in,
                              void* d_out, int out_size, void* d_ws, size_t ws_size,
                              hipStream_t stream){
  (void)in_sizes; (void)n_in; (void)out_size; (void)ws_size;
  const int*   adj = (const int*)d_in[0];
  const float* x   = (const float*)d_in[1];
  const float* W   = (const float*)d_in[2];
  const float* a   = (const float*)d_in[3];
  float* out = (float*)d_out;
  char* ws = (char*)d_ws;

  float* h     = (float*)(ws);                                 // 2 MB
  short* VbfSw = (short*)(ws + (2u << 20));                    // 1 MB
  short* VTsw  = (short*)(ws + (3u << 20));                    // 1 MB
  float* F     = (float*)(ws + (4u << 20));                    // 32 KB
  float* V2arr = (float*)(ws + (4u << 20) + (32u << 10));      // 32 KB
  float2* EG   = (float2*)(ws + (4u << 20) + (64u << 10));     // 64 KB
  float* Vpart = (float*)(ws + (4u << 20) + (128u << 10));     // 32 KB
  float* Pv2   = (float*)(ws + (4u << 20) + (160u << 10));     // 512 B
  float* Pg    = (float*)(ws + (4u << 20) + (161u << 10));     // 512 B

  k_h    <<<256, 256, 0, stream>>>(x, W, h);
  k_prep <<<128, 256, 0, stream>>>(h, a, VbfSw, VTsw, F, EG, V2arr, Pv2, Pg, Vpart);
  k_fused<<<512, 512, 0, stream>>>(adj, EG, V2arr, F, Pv2, Pg, Vpart, VbfSw, VTsw, out);
}

// Round 8
// 137.858 us; speedup vs baseline: 1.0623x; 1.0623x over previous
//
#include <hip/hip_runtime.h>
#include <hip/hip_bf16.h>

typedef __attribute__((ext_vector_type(8))) short s8v;   // 8 x bf16 = 4 VGPR
typedef __attribute__((ext_vector_type(4))) short s4v;   // 4 x bf16 = 2 VGPR
typedef __attribute__((ext_vector_type(4))) float f4v;   // 4 x f32

static __device__ __forceinline__ short f2bf(float f){
  unsigned int u = __float_as_uint(f);
  u = (u + 0x7FFFu + ((u >> 16) & 1u)) >> 16;   // RNE f32 -> bf16
  return (short)u;
}

static __device__ __forceinline__ s4v pack4(float a, float b, float c, float d){
  union { s4v v; __hip_bfloat162 h[2]; } u;
  u.h[0] = __float22bfloat162_rn(make_float2(a, b));
  u.h[1] = __float22bfloat162_rn(make_float2(c, d));
  return u.v;
}

static __device__ __forceinline__ f4v mfma16(s4v a, s4v b, f4v c){
  return __builtin_amdgcn_mfma_f32_16x16x16bf16_1k(a, b, c, 0, 0, 0);
}

// ---------- K1: h = x @ W (8 rows per wave) ----------
__global__ __launch_bounds__(256) void k_h(const float* __restrict__ x,
                                           const float* __restrict__ W,
                                           float* __restrict__ h){
  int wid = threadIdx.x >> 6, lane = threadIdx.x & 63;
  int r0 = (blockIdx.x * 4 + wid) * 8;
  const float* xr = x + (size_t)r0 * 512;
  float acc[8] = {0.f,0.f,0.f,0.f,0.f,0.f,0.f,0.f};
  #pragma unroll 4
  for (int k = 0; k < 512; ++k){
    float wv = W[k*64 + lane];
    #pragma unroll
    for (int r = 0; r < 8; ++r)
      acc[r] = fmaf(xr[(size_t)r*512 + k], wv, acc[r]);
  }
  #pragma unroll
  for (int r = 0; r < 8; ++r)
    h[(size_t)(r0 + r)*64 + lane] = acc[r];
}

// ---------- K2: per-64-row tile: swizzled V frags, per-row F/EG/V2, block partials ----------
__global__ __launch_bounds__(256) void k_prep(const float* __restrict__ h,
                                              const float* __restrict__ a,
                                              short* __restrict__ VbfSw,
                                              short* __restrict__ VTsw,
                                              float* __restrict__ F,
                                              float2* __restrict__ EG,
                                              float* __restrict__ V2arr,
                                              float* __restrict__ Pv2,
                                              float* __restrict__ Pg,
                                              float* __restrict__ Vpart){
  __shared__ float t[64][65];
  const int tid = threadIdx.x;
  const int lane = tid & 63, w = tid >> 6;
  const int lo = lane & 15, hi = lane >> 4;
  const int i0 = blockIdx.x * 64;
  #pragma unroll
  for (int it = 0; it < 16; ++it){
    int r = w * 16 + it;
    t[r][lane] = h[(size_t)(i0 + r) * 64 + lane];
  }
  __syncthreads();
  // VbfSw: dot A-frag layout
  #pragma unroll
  for (int ks = 0; ks < 2; ++ks){
    s8v o;
    #pragma unroll
    for (int e = 0; e < 8; ++e)
      o[e] = f2bf(t[w*16 + lo][ks*32 + hi*8 + e]);
    *(s8v*)(VbfSw + ((size_t)(i0/16 + w)*2 + ks)*512 + lane*8) = o;
  }
  // VTsw: PV A-frag layout
  const int p = w >> 1;
  #pragma unroll
  for (int oo = 0; oo < 2; ++oo){
    const int ot = (w & 1) * 2 + oo;
    s8v o;
    #pragma unroll
    for (int e = 0; e < 8; ++e){
      int parity = e >> 2, q = e & 3;
      o[e] = f2bf(t[(p*2 + parity)*16 + hi*4 + q][ot*16 + lo]);
    }
    *(s8v*)(VTsw + ((size_t)(i0/32 + p)*4 + ot)*512 + lane*8) = o;
  }
  // per-row stats + block partials + colsum (wave 0)
  if (tid < 64){
    const int r = tid;
    float f = 0.f, g = 0.f, v2 = 0.f;
    #pragma unroll 8
    for (int o = 0; o < 64; ++o){
      float hv = t[r][o];
      f  = fmaf(hv, a[o],      f);
      g  = fmaf(hv, a[64 + o], g);
      v2 = fmaf(hv, hv,        v2);
    }
    const int row = i0 + r;
    F[row] = f;
    V2arr[row] = v2;
    EG[row] = make_float2(__expf(g), __expf(0.2f * g));
    float vmin = v2, gmx = g;
    #pragma unroll
    for (int off = 32; off; off >>= 1){
      vmin = fminf(vmin, __shfl_xor(vmin, off));
      gmx  = fmaxf(gmx,  __shfl_xor(gmx,  off));
    }
    if (r == 0){ Pv2[blockIdx.x] = vmin; Pg[blockIdx.x] = gmx; }
    float cs = 0.f;
    #pragma unroll 8
    for (int rr = 0; rr < 64; ++rr) cs += t[rr][tid];
    Vpart[(size_t)blockIdx.x * 64 + tid] = cs;
  }
}

// ---------- K3: fully fused: softmax-denom + A@V sweep (adj read direct, once),
// Cauchy-Schwarz-gated robust passes, elu epilogue.
__global__ __launch_bounds__(512, 4) void k_fused(
    const int* __restrict__ adj,
    const float2* __restrict__ EG, const float* __restrict__ V2arr,
    const float* __restrict__ F,
    const float* __restrict__ Pv2, const float* __restrict__ Pg,
    const float* __restrict__ Vpart,
    const short* __restrict__ VbfSw, const short* __restrict__ VTsw,
    float* __restrict__ out)
{
  __shared__ float numT[8][64][16];
  __shared__ float denL[8][16];
  __shared__ float Mlds[16][68];
  __shared__ float M1L[16][68];
  __shared__ __align__(16) short Mb16[16][64];
  __shared__ float CiL[16], rm2L[16], uaiL[16];
  __shared__ float VmeanL[64];
  __shared__ float gmaxS, v2minS;
  __shared__ int actL, chgL, emptyL;

  const int tid  = threadIdx.x;
  const int w    = tid >> 6;
  const int lane = tid & 63;
  const int lo = lane & 15, hi = lane >> 4;
  const int r0 = blockIdx.x << 4;
  const int i  = r0 + lo;

  // global min/max from per-block partials (no atomics)
  if (tid < 64){
    float v = fminf(Pv2[tid], Pv2[tid + 64]);
    float g = fmaxf(Pg[tid],  Pg[tid + 64]);
    #pragma unroll
    for (int off = 32; off; off >>= 1){
      v = fminf(v, __shfl_xor(v, off));
      g = fmaxf(g, __shfl_xor(g, off));
    }
    if (tid == 0){ v2minS = v; gmaxS = g; actL = 0; emptyL = 0; }
  }
  __syncthreads();

  const float fi   = F[i];
  const float gmax = gmaxS;
  const float z    = fi + gmax;
  const float B    = fmaxf(z, 0.2f * z);          // >= leaky(fi+gj) for all j
  const float e1s  = __expf(fi - B);
  const float e2s  = __expf(0.2f * fi - B);

  const int* arow = adj + (size_t)i * 8192 + hi*4;

  const f4v zero4 = {0.f,0.f,0.f,0.f};
  f4v pacc[4] = {zero4, zero4, zero4, zero4};
  float pden = 0.f;

  // ---- Phase AB: one sweep = softmax denom + A@V; adj streamed directly ----
  for (int c = w; c < 128; c += 8){
    const int* ap = arow + (c << 6);
    s4v wwpk[4];
    #pragma unroll
    for (int nt = 0; nt < 4; ++nt){
      const int jb = (c << 6) + nt*16 + hi*4;
      const int4 av4 = *(const int4*)(ap + nt*16);
      const int ab[4] = {av4.x, av4.y, av4.z, av4.w};
      const f4v u0 = *(const f4v*)(EG + jb);       // eg1_0,eg2_0,eg1_1,eg2_1
      const f4v u1 = *(const f4v*)(EG + jb + 2);
      const float ega[4] = {u0[0], u0[2], u1[0], u1[2]};
      const float egb[4] = {u0[1], u0[3], u1[1], u1[3]};
      float wwv[4];
      #pragma unroll
      for (int q = 0; q < 4; ++q){
        float u = fmaxf(e1s * ega[q], e2s * egb[q]);   // exp(leaky(fi+gj) - B)
        u = ab[q] ? u : 0.f;
        pden += u;
        wwv[q] = u;
      }
      wwpk[nt] = pack4(wwv[0], wwv[1], wwv[2], wwv[3]);
    }
    const short* vt = VTsw + (size_t)c*4096 + lane*8;
    #pragma unroll
    for (int p = 0; p < 2; ++p){
      #pragma unroll
      for (int ot = 0; ot < 4; ++ot){
        s8v v8 = *(const s8v*)(vt + (p*4 + ot)*512);
        s4v aLo = {v8[0], v8[1], v8[2], v8[3]};
        s4v aHi = {v8[4], v8[5], v8[6], v8[7]};
        pacc[ot] = mfma16(aLo, wwpk[2*p],   pacc[ot]);
        pacc[ot] = mfma16(aHi, wwpk[2*p+1], pacc[ot]);
      }
    }
  }

  pden += __shfl_xor(pden, 16);
  pden += __shfl_xor(pden, 32);
  if (lane < 16) denL[w][lane] = pden;
  #pragma unroll
  for (int ot = 0; ot < 4; ++ot)
    #pragma unroll
    for (int q = 0; q < 4; ++q)
      numT[w][ot*16 + hi*4 + q][lo] = pacc[ot][q];
  __syncthreads();

  // ---- reduce -> M1, Ci, empty detection ----
  {
    const int ii = tid & 15;
    const int o  = tid >> 4;            // 0..31
    float den = 0.f;
    #pragma unroll
    for (int w2 = 0; w2 < 8; ++w2) den += denL[w2][ii];
    if (o == 0){
      uaiL[ii] = (den <= 0.f) ? (1.0f / 8192.0f) : 0.f;
      if (den <= 0.f) emptyL = 1;
    }
    den = fmaxf(den, 1e-30f);
    const float rden = 1.0f / den;
    #pragma unroll
    for (int rep = 0; rep < 2; ++rep){
      const int oo = o + rep*32;
      float num = 0.f;
      #pragma unroll
      for (int w2 = 0; w2 < 8; ++w2) num += numT[w2][oo][ii];
      Mlds[ii][oo] = num * rden;
    }
    if (tid < 16){
      float fb = F[r0 + tid];
      float zb = fb + gmax;
      float Bb = fmaxf(zb, 0.2f * zb);
      CiL[tid] = Bb + __logf(den);      // softmax log-normalizer
    }
  }
  __syncthreads();

  // ---- empty-row fixup: M1 = colmean(V) (uniform attention) ----
  if (emptyL){
    if (tid < 64){
      float s = 0.f;
      for (int b = 0; b < 128; ++b) s += Vpart[(size_t)b*64 + tid];
      VmeanL[tid] = s * (1.0f / 8192.0f);
    }
    __syncthreads();
    {
      const int r = tid >> 5, c2 = (tid & 31) << 1;
      if (uaiL[r] > 0.f){ Mlds[r][c2] = VmeanL[c2]; Mlds[r][c2+1] = VmeanL[c2+1]; }
    }
    __syncthreads();
  }

  // ---- rm2 + activity (Cauchy-Schwarz: row inactive if sqrt(rm2) <= sqrt(v2min)-3.85) ----
  if (tid < 16){
    float s2 = 0.f;
    #pragma unroll 8
    for (int o = 0; o < 64; ++o) s2 = fmaf(Mlds[tid][o], Mlds[tid][o], s2);
    rm2L[tid] = s2;
    if (sqrtf(s2) > sqrtf(v2minS) - 3.85f) actL = 1;
  }
  __syncthreads();

  if (actL){
    {
      const int r = tid >> 5, c2 = (tid & 31) << 1;
      float a0 = Mlds[r][c2], a1 = Mlds[r][c2+1];
      M1L[r][c2] = a0;  M1L[r][c2+1] = a1;
      Mb16[r][c2] = f2bf(a0); Mb16[r][c2+1] = f2bf(a1);
    }
    const float e1c = __expf(fi - CiL[lo]);
    const float e2c = __expf(0.2f * fi - CiL[lo]);
    const float uai = uaiL[lo];
    __syncthreads();

    for (int pass = 0; pass < 3; ++pass){
      if (tid == 0) chgL = 0;
      __syncthreads();
      const float rm2 = rm2L[lo];
      s8v bM[2];
      #pragma unroll
      for (int ks = 0; ks < 2; ++ks)
        bM[ks] = *(const s8v*)&Mb16[lo][ks*32 + hi*8];

      f4v cacc[4] = {zero4, zero4, zero4, zero4};
      float cden = 0.f;

      for (int c = w; c < 128; c += 8){
        // dot: S^T = V @ M^T
        f4v acc[4] = {zero4, zero4, zero4, zero4};
        const short* vb = VbfSw + (size_t)c*4096 + lane*8;
        #pragma unroll
        for (int nt = 0; nt < 4; ++nt){
          #pragma unroll
          for (int ks = 0; ks < 2; ++ks){
            s8v av = *(const s8v*)(vb + (nt*2 + ks)*512);
            acc[nt] = __builtin_amdgcn_mfma_f32_16x16x32_bf16(av, bM[ks], acc[nt], 0, 0, 0);
          }
        }
        // d2 + threshold (w > eps only possible if d2 < 14.716; margin -> 16)
        f4v d2s[4];
        float dmin = 1e30f;
        #pragma unroll
        for (int nt = 0; nt < 4; ++nt){
          const int jb = (c << 6) + nt*16 + hi*4;
          const f4v v2q = *(const f4v*)(V2arr + jb);
          #pragma unroll
          for (int q = 0; q < 4; ++q){
            float d2 = fmaf(-2.0f, acc[nt][q], rm2 + v2q[q]);
            d2s[nt][q] = d2;
            dmin = fminf(dmin, d2);
          }
        }
        if (__any(dmin < 16.0f)){
          // rare slow path: correction terms; adj re-read (L3-warm)
          const int* ap = arow + (c << 6);
          s4v wwpk[4];
          #pragma unroll
          for (int nt = 0; nt < 4; ++nt){
            const int jb = (c << 6) + nt*16 + hi*4;
            const int4 av4 = *(const int4*)(ap + nt*16);
            const int ab[4] = {av4.x, av4.y, av4.z, av4.w};
            const f4v u0 = *(const f4v*)(EG + jb);
            const f4v u1 = *(const f4v*)(EG + jb + 2);
            const float ega[4] = {u0[0], u0[2], u1[0], u1[2]};
            const float egb[4] = {u0[1], u0[3], u1[1], u1[3]};
            float wwv[4];
            #pragma unroll
            for (int q = 0; q < 4; ++q){
              float A = fmaxf(e1c * ega[q], e2c * egb[q]);
              A = ab[q] ? A : uai;
              float dist  = sqrtf(fmaxf(d2s[nt][q], 0.f));
              float delta = fmaxf(__builtin_amdgcn_rcpf(dist + 0.01f) - 0.26f, 0.f);
              float ww = delta * A;
              cden += ww;
              wwv[q] = ww;
            }
            wwpk[nt] = pack4(wwv[0], wwv[1], wwv[2], wwv[3]);
          }
          const short* vt = VTsw + (size_t)c*4096 + lane*8;
          #pragma unroll
          for (int p = 0; p < 2; ++p){
            #pragma unroll
            for (int ot = 0; ot < 4; ++ot){
              s8v v8 = *(const s8v*)(vt + (p*4 + ot)*512);
              s4v aLo = {v8[0], v8[1], v8[2], v8[3]};
              s4v aHi = {v8[4], v8[5], v8[6], v8[7]};
              cacc[ot] = mfma16(aLo, wwpk[2*p],   cacc[ot]);
              cacc[ot] = mfma16(aHi, wwpk[2*p+1], cacc[ot]);
            }
          }
        }
      }

      if (__any(cden > 0.f)) chgL = 1;
      __syncthreads();
      if (chgL){
        float cd = cden;
        cd += __shfl_xor(cd, 16);
        cd += __shfl_xor(cd, 32);
        if (lane < 16) denL[w][lane] = cd;
        #pragma unroll
        for (int ot = 0; ot < 4; ++ot)
          #pragma unroll
          for (int q = 0; q < 4; ++q)
            numT[w][ot*16 + hi*4 + q][lo] = cacc[ot][q];
        __syncthreads();
        {
          const int ii = tid & 15;
          const int o  = tid >> 4;
          float den = 0.f;
          #pragma unroll
          for (int w2 = 0; w2 < 8; ++w2) den += denL[w2][ii];
          const float rden = 1.0f / (0.01f + den);
          #pragma unroll
          for (int rep = 0; rep < 2; ++rep){
            const int oo = o + rep*32;
            float num = 0.f;
            #pragma unroll
            for (int w2 = 0; w2 < 8; ++w2) num += numT[w2][oo][ii];
            Mlds[ii][oo] = fmaf(0.01f, M1L[ii][oo], num) * rden;
          }
        }
        __syncthreads();
        {
          const int r = tid >> 5, c2 = (tid & 31) << 1;
          Mb16[r][c2]   = f2bf(Mlds[r][c2]);
          Mb16[r][c2+1] = f2bf(Mlds[r][c2+1]);
        }
        if (tid < 16){
          float s2 = 0.f;
          #pragma unroll 8
          for (int o = 0; o < 64; ++o) s2 = fmaf(Mlds[tid][o], Mlds[tid][o], s2);
          rm2L[tid] = s2;
        }
        __syncthreads();
      }
    }
  }
  __syncthreads();

  // ---- epilogue: elu -> out ----
  #pragma unroll
  for (int rr = 0; rr < 2; ++rr){
    const int ir = w*2 + rr;
    const float v = Mlds[ir][lane];
    out[(size_t)(r0 + ir) * 64 + lane] = (v > 0.f) ? v : (__expf(v) - 1.0f);
  }
}

extern "C" void kernel_launch(void* const* d_in, const int* in_sizes, int n_in,
                              void* d_out, int out_size, void* d_ws, size_t ws_size,
                              hipStream_t stream){
  (void)in_sizes; (void)n_in; (void)out_size; (void)ws_size;
  const int*   adj = (const int*)d_in[0];
  const float* x   = (const float*)d_in[1];
  const float* W   = (const float*)d_in[2];
  const float* a   = (const float*)d_in[3];
  float* out = (float*)d_out;
  char* ws = (char*)d_ws;

  float* h     = (float*)(ws);                                 // 2 MB
  short* VbfSw = (short*)(ws + (2u << 20));                    // 1 MB
  short* VTsw  = (short*)(ws + (3u << 20));                    // 1 MB
  float* F     = (float*)(ws + (4u << 20));                    // 32 KB
  float* V2arr = (float*)(ws + (4u << 20) + (32u << 10));      // 32 KB
  float2* EG   = (float2*)(ws + (4u << 20) + (64u << 10));     // 64 KB
  float* Vpart = (float*)(ws + (4u << 20) + (128u << 10));     // 32 KB
  float* Pv2   = (float*)(ws + (4u << 20) + (160u << 10));     // 512 B
  float* Pg    = (float*)(ws + (4u << 20) + (161u << 10));     // 512 B

  k_h    <<<256, 256, 0, stream>>>(x, W, h);
  k_prep <<<128, 256, 0, stream>>>(h, a, VbfSw, VTsw, F, EG, V2arr, Pv2, Pg, Vpart);
  k_fused<<<512, 512, 0, stream>>>(adj, EG, V2arr, F, Pv2, Pg, Vpart, VbfSw, VTsw, out);
}